// Round 11
// baseline (155.589 us; speedup 1.0000x reference)
//
#include <hip/hip_runtime.h>

#define IMH 384
#define IMW 384
#define OH 378
#define OW 378
#define NB 64
#define SROWS 16
#define INROWS 22          // SROWS + 6
#define NSTRIP 24          // 24*16 = 384 >= 378 (last strip masked)
#define BLOCK 256          // 4 waves = 16 DPP groups of 16 lanes
#define GSTRIDE 26         // output cols per group (13 lanes x 2 cols)

// Round 11: waves_per_eu(6,6) + SROWS=16 (1536 blocks = exactly 6 waves/EU).
// History of allocator behavior on this kernel:
//   (none)   -> 32 VGPR, remat re-loads, latency-bound (R8, 41us)
//   (4,4)    -> register-resident, no spills, 16 waves/CU, ~36us (R9)
//   (6,8)    -> targets max=8 (64-VGPR budget), clamps to 40 VGPR and
//               SPILLS 20.5 MB to scratch, 64.5us (R10 regression)
//   (b,8)/launch_bounds(...,8) -> same spill pathology (R3)
// => only pinned min=max with headroom works. (6,6) = 85-VGPR budget vs
// ~60-reg live set: no spill incentive, residency 16->24 waves/CU (1.5x).

template <int CTRL>
__device__ __forceinline__ float dpp_sh(float v) {
    return __int_as_float(__builtin_amdgcn_update_dpp(
        0, __float_as_int(v), CTRL, 0xf, 0xf, true));
}

__device__ __forceinline__ float2 f2add(float2 a, float2 b) { return make_float2(a.x + b.x, a.y + b.y); }
__device__ __forceinline__ float2 f2sub(float2 a, float2 b) { return make_float2(a.x - b.x, a.y - b.y); }
__device__ __forceinline__ float2 f2mul(float2 a, float2 b) { return make_float2(a.x * b.x, a.y * b.y); }
__device__ __forceinline__ float2 f2fma(float2 a, float2 b, float2 c) {
    return make_float2(fmaf(a.x, b.x, c.x), fmaf(a.y, b.y, c.y));
}
__device__ __forceinline__ float2 f2fnma(float2 a, float2 b, float2 c) {  // c - a*b
    return make_float2(fmaf(-a.x, b.x, c.x), fmaf(-a.y, b.y, c.y));
}
__device__ __forceinline__ float2 f2fms(float2 a, float s, float2 c) {    // a*s - c
    return make_float2(fmaf(a.x, s, -c.x), fmaf(a.y, s, -c.y));
}
__device__ __forceinline__ float2 f2s(float s) { return make_float2(s, s); }

__global__ __launch_bounds__(BLOCK)
__attribute__((amdgpu_waves_per_eu(6, 6)))
void ssim_kernel(
    const float* __restrict__ X, const float* __restrict__ Y,
    const float* __restrict__ data_range, float* __restrict__ acc)
{
    const int tid = threadIdx.x;
    const int b   = blockIdx.z;
    const int y0  = blockIdx.y * SROWS;

    const float* __restrict__ Xb = X + b * (IMH * IMW);
    const float* __restrict__ Yb = Y + b * (IMH * IMW);

    const int g   = tid >> 4;                 // DPP group 0..15
    const int j   = tid & 15;                 // lane within group
    const int ce  = g * GSTRIDE + 2 * j;      // lane's even column (global)
    const int cin = min(ce, IMW - 2);         // clamped, even -> 8B aligned
    const float2 vmask = make_float2(
        ((j <= 12) && (ce     < OW)) ? 1.f : 0.f,
        ((j <= 12) && (ce + 1 < OW)) ? 1.f : 0.f);

    const float L     = data_range[b];
    const float C1    = (0.01f * L) * (0.01f * L);
    const float C2    = (0.03f * L) * (0.03f * L);
    const float inv49 = 1.0f / 49.0f;
    const float covn  = 49.0f / 48.0f;

    // per-lane raw history of its 2 columns + running vertical sums
    float2 xh[7], yh[7];
    #pragma unroll
    for (int k = 0; k < 7; ++k) { xh[k] = f2s(0.f); yh[k] = f2s(0.f); }
    float2 V0 = f2s(0.f), V1 = f2s(0.f), V2 = f2s(0.f),
           V3 = f2s(0.f), V4 = f2s(0.f);
    float2 ls2 = f2s(0.f);

    // depth-2 explicit pipeline: rows r+1 and r+2 in flight
    float2 px[2], py[2];
    {
        const int r0 = min(y0,     IMH - 1);
        const int r1 = min(y0 + 1, IMH - 1);
        px[0] = *(const float2*)(Xb + r0 * IMW + cin);
        py[0] = *(const float2*)(Yb + r0 * IMW + cin);
        px[1] = *(const float2*)(Xb + r1 * IMW + cin);
        py[1] = *(const float2*)(Yb + r1 * IMW + cin);
    }

    #pragma unroll
    for (int r = 0; r < INROWS; ++r) {
        const int slot = r & 1;                        // static after unroll
        const float2 x = px[slot], y = py[slot];
        if (r + 2 < INROWS) {                          // refill consumed slot
            const int ri = min(y0 + r + 2, IMH - 1);   // uniform row clamp
            px[slot] = *(const float2*)(Xb + ri * IMW + cin);
            py[slot] = *(const float2*)(Yb + ri * IMW + cin);
        }

        // vertical 7-row slide on both columns (pk-f32 eligible)
        const int ks = r % 7;                          // static after unroll
        const float2 xo = xh[ks], yo = yh[ks];
        V0 = f2add(V0, f2sub(x, xo));
        V1 = f2add(V1, f2sub(y, yo));
        V2 = f2fma(x, x, V2);  V2 = f2fnma(xo, xo, V2);
        V3 = f2fma(x, y, V3);  V3 = f2fnma(xo, yo, V3);
        V4 = f2fma(y, y, V4);  V4 = f2fnma(yo, yo, V4);
        xh[ks] = x; yh[ks] = y;

        // output row o = y0+r-6; uniform guard (384 > 378 tiling overhang)
        if (r >= 6 && (y0 + r - 6) < OH) {
            // horizontal 7-window sums for even+odd output cols
            const float2 Vv[5] = {V0, V1, V2, V3, V4};
            float Se[5], So[5];
            #pragma unroll
            for (int p = 0; p < 5; ++p) {
                const float e  = Vv[p].x;
                const float pp = Vv[p].x + Vv[p].y;        // lane pair sum
                float A = pp + dpp_sh<0x101>(pp);          // pp(l)+pp(l+1)
                A      += dpp_sh<0x102>(pp);               // +pp(l+2)
                Se[p] = A + dpp_sh<0x103>(e);              // cols 2l..2l+6
                So[p] = (A - e) + dpp_sh<0x103>(pp);       // cols 2l+1..2l+7
            }
            const float2 S0 = make_float2(Se[0], So[0]);
            const float2 S1 = make_float2(Se[1], So[1]);
            const float2 S2 = make_float2(Se[2], So[2]);
            const float2 S3 = make_float2(Se[3], So[3]);
            const float2 S4 = make_float2(Se[4], So[4]);

            float2 ux   = f2mul(S0, f2s(inv49));
            float2 uy   = f2mul(S1, f2s(inv49));
            float2 uxux = f2mul(ux, ux);
            float2 uyuy = f2mul(uy, uy);
            float2 uxuy = f2mul(ux, uy);
            float2 vx   = f2mul(f2fms(S2, inv49, uxux), f2s(covn));
            float2 vy   = f2mul(f2fms(S4, inv49, uyuy), f2s(covn));
            float2 vxy  = f2mul(f2fms(S3, inv49, uxuy), f2s(covn));
            float2 N1   = f2fma(f2s(2.f), uxuy, f2s(C1));
            float2 N2   = f2fma(f2s(2.f), vxy, f2s(C2));
            float2 D1   = f2add(f2add(uxux, uyuy), f2s(C1));
            float2 D2   = f2add(f2add(vx, vy), f2s(C2));
            float2 num  = f2mul(N1, N2);
            float2 den  = f2mul(D1, D2);
            // one rcp for both columns: se = nx*dy/(dx*dy), so = ny*dx/(dx*dy)
            const float rdd = __builtin_amdgcn_rcpf(den.x * den.y);
            float2 s2 = make_float2(num.x * den.y * rdd,
                                    num.y * den.x * rdd);
            ls2 = f2fma(s2, vmask, ls2);
        }
    }

    float lsum = ls2.x + ls2.y;

    // ---- Block reduction: wave64 shuffle -> LDS -> one atomic/block ----
    __shared__ float red[BLOCK / 64];
    #pragma unroll
    for (int off = 32; off > 0; off >>= 1)
        lsum += __shfl_down(lsum, off, 64);
    if ((tid & 63) == 0) red[tid >> 6] = lsum;
    __syncthreads();
    if (tid == 0) {
        float bs = 0.f;
        #pragma unroll
        for (int k = 0; k < BLOCK / 64; ++k) bs += red[k];
        atomicAdd(acc, bs);
    }
}

__global__ void finalize_kernel(const float* __restrict__ acc,
                                float* __restrict__ out)
{
    out[0] = 1.0f - acc[0] * (1.0f / (float)(NB * OH * OW));
}

extern "C" void kernel_launch(void* const* d_in, const int* in_sizes, int n_in,
                              void* d_out, int out_size, void* d_ws, size_t ws_size,
                              hipStream_t stream) {
    const float* X  = (const float*)d_in[0];
    const float* Y  = (const float*)d_in[1];
    const float* dr = (const float*)d_in[2];
    float* out = (float*)d_out;
    float* acc = (float*)d_ws;

    hipMemsetAsync(acc, 0, sizeof(float), stream);

    dim3 grid(1, NSTRIP, NB);   // 24 x 64 = 1536 blocks
    dim3 block(BLOCK);          // 256 threads = 4 waves
    ssim_kernel<<<grid, block, 0, stream>>>(X, Y, dr, acc);
    finalize_kernel<<<1, 1, 0, stream>>>(acc, out);
}

// Round 12
// 123.580 us; speedup vs baseline: 1.2590x; 1.2590x over previous
//
#include <hip/hip_runtime.h>

#define IMH 384
#define IMW 384
#define OH 378
#define OW 378
#define NB 64
#define SROWS 12
#define INROWS 18          // SROWS + 6
#define NSTRIP 32          // 32*12 = 384 >= 378 (last strip masked)
#define BLOCK 256          // 4 waves = 16 DPP groups of 16 lanes
#define GSTRIDE 26         // output cols per group (13 lanes x 2 cols)

// Round 12: history ring in LDS, own-slot, barrier-free. Allocator dossier
// (R3..R11): live set >40 floats => gfx950 RA either remats (32 VGPR,
// serialized re-loads) or spills MB-scale scratch (40 VGPR + 20-70 MB
// WRITE), under every waves_per_eu/launch_bounds variant except (4,4).
// Fix is structural: the 28-reg raw history moves to ring[7][256] float4
// (x.xy|y.xy). Lane reads its OWN slot (row r-7, 1x ds_read_b128) and
// overwrites it (1x ds_write_b128) - program order per lane, no barriers,
// consecutive-lane b128 = conflict-free. Live set ~38 floats fits the
// natural envelope: no attribute, no spill, no remat. LDS 28.7 KB caps
// 5 blocks/CU = 20 waves/CU (> R9's 16). DS ops overlap VALU pipe.

template <int CTRL>
__device__ __forceinline__ float dpp_sh(float v) {
    return __int_as_float(__builtin_amdgcn_update_dpp(
        0, __float_as_int(v), CTRL, 0xf, 0xf, true));
}

__device__ __forceinline__ float2 f2add(float2 a, float2 b) { return make_float2(a.x + b.x, a.y + b.y); }
__device__ __forceinline__ float2 f2sub(float2 a, float2 b) { return make_float2(a.x - b.x, a.y - b.y); }
__device__ __forceinline__ float2 f2mul(float2 a, float2 b) { return make_float2(a.x * b.x, a.y * b.y); }
__device__ __forceinline__ float2 f2fma(float2 a, float2 b, float2 c) {
    return make_float2(fmaf(a.x, b.x, c.x), fmaf(a.y, b.y, c.y));
}
__device__ __forceinline__ float2 f2fnma(float2 a, float2 b, float2 c) {  // c - a*b
    return make_float2(fmaf(-a.x, b.x, c.x), fmaf(-a.y, b.y, c.y));
}
__device__ __forceinline__ float2 f2fms(float2 a, float s, float2 c) {    // a*s - c
    return make_float2(fmaf(a.x, s, -c.x), fmaf(a.y, s, -c.y));
}
__device__ __forceinline__ float2 f2s(float s) { return make_float2(s, s); }

__global__ __launch_bounds__(BLOCK) void ssim_kernel(
    const float* __restrict__ X, const float* __restrict__ Y,
    const float* __restrict__ data_range, float* __restrict__ acc)
{
    // 7-row raw-history ring: slot [k][lane] holds (x.x,x.y,y.x,y.y)
    __shared__ __align__(16) float4 ring[7][BLOCK];   // 28672 B
    __shared__ float red[BLOCK / 64];

    const int tid = threadIdx.x;
    const int b   = blockIdx.z;
    const int y0  = blockIdx.y * SROWS;

    const float* __restrict__ Xb = X + b * (IMH * IMW);
    const float* __restrict__ Yb = Y + b * (IMH * IMW);

    const int g   = tid >> 4;                 // DPP group 0..15
    const int j   = tid & 15;                 // lane within group
    const int ce  = g * GSTRIDE + 2 * j;      // lane's even column (global)
    const int cin = min(ce, IMW - 2);         // clamped, even -> 8B aligned
    const float2 vmask = make_float2(
        ((j <= 12) && (ce     < OW)) ? 1.f : 0.f,
        ((j <= 12) && (ce + 1 < OW)) ? 1.f : 0.f);

    const float L     = data_range[b];
    const float C1    = (0.01f * L) * (0.01f * L);
    const float C2    = (0.03f * L) * (0.03f * L);
    const float inv49 = 1.0f / 49.0f;
    const float covn  = 49.0f / 48.0f;

    // zero own ring slots (lane-private; no barrier needed anywhere)
    #pragma unroll
    for (int k = 0; k < 7; ++k)
        ring[k][tid] = make_float4(0.f, 0.f, 0.f, 0.f);

    float2 V0 = f2s(0.f), V1 = f2s(0.f), V2 = f2s(0.f),
           V3 = f2s(0.f), V4 = f2s(0.f);
    float2 ls2 = f2s(0.f);

    // depth-2 explicit pipeline: rows r+1 and r+2 in flight
    float2 px[2], py[2];
    {
        const int r0 = min(y0,     IMH - 1);
        const int r1 = min(y0 + 1, IMH - 1);
        px[0] = *(const float2*)(Xb + r0 * IMW + cin);
        py[0] = *(const float2*)(Yb + r0 * IMW + cin);
        px[1] = *(const float2*)(Xb + r1 * IMW + cin);
        py[1] = *(const float2*)(Yb + r1 * IMW + cin);
    }

    #pragma unroll
    for (int r = 0; r < INROWS; ++r) {
        const int slot = r & 1;                        // static after unroll
        const float2 x = px[slot], y = py[slot];
        if (r + 2 < INROWS) {                          // refill consumed slot
            const int ri = min(y0 + r + 2, IMH - 1);   // uniform row clamp
            px[slot] = *(const float2*)(Xb + ri * IMW + cin);
            py[slot] = *(const float2*)(Yb + ri * IMW + cin);
        }

        // ring: read retiring row r-7 from own slot, overwrite with row r
        const int ks = r % 7;                          // static after unroll
        const float4 old = ring[ks][tid];              // ds_read_b128
        ring[ks][tid] = make_float4(x.x, x.y, y.x, y.y);  // ds_write_b128
        const float2 xo = make_float2(old.x, old.y);
        const float2 yo = make_float2(old.z, old.w);

        // vertical 7-row slide on both columns (pk-f32 eligible)
        V0 = f2add(V0, f2sub(x, xo));
        V1 = f2add(V1, f2sub(y, yo));
        V2 = f2fma(x, x, V2);  V2 = f2fnma(xo, xo, V2);
        V3 = f2fma(x, y, V3);  V3 = f2fnma(xo, yo, V3);
        V4 = f2fma(y, y, V4);  V4 = f2fnma(yo, yo, V4);

        // output row o = y0+r-6; uniform guard (384 > 378 tiling overhang)
        if (r >= 6 && (y0 + r - 6) < OH) {
            // horizontal 7-window sums for even+odd output cols
            const float2 Vv[5] = {V0, V1, V2, V3, V4};
            float Se[5], So[5];
            #pragma unroll
            for (int p = 0; p < 5; ++p) {
                const float e  = Vv[p].x;
                const float pp = Vv[p].x + Vv[p].y;        // lane pair sum
                float A = pp + dpp_sh<0x101>(pp);          // pp(l)+pp(l+1)
                A      += dpp_sh<0x102>(pp);               // +pp(l+2)
                Se[p] = A + dpp_sh<0x103>(e);              // cols 2l..2l+6
                So[p] = (A - e) + dpp_sh<0x103>(pp);       // cols 2l+1..2l+7
            }
            const float2 S0 = make_float2(Se[0], So[0]);
            const float2 S1 = make_float2(Se[1], So[1]);
            const float2 S2 = make_float2(Se[2], So[2]);
            const float2 S3 = make_float2(Se[3], So[3]);
            const float2 S4 = make_float2(Se[4], So[4]);

            float2 ux   = f2mul(S0, f2s(inv49));
            float2 uy   = f2mul(S1, f2s(inv49));
            float2 uxux = f2mul(ux, ux);
            float2 uyuy = f2mul(uy, uy);
            float2 uxuy = f2mul(ux, uy);
            float2 vx   = f2mul(f2fms(S2, inv49, uxux), f2s(covn));
            float2 vy   = f2mul(f2fms(S4, inv49, uyuy), f2s(covn));
            float2 vxy  = f2mul(f2fms(S3, inv49, uxuy), f2s(covn));
            float2 N1   = f2fma(f2s(2.f), uxuy, f2s(C1));
            float2 N2   = f2fma(f2s(2.f), vxy, f2s(C2));
            float2 D1   = f2add(f2add(uxux, uyuy), f2s(C1));
            float2 D2   = f2add(f2add(vx, vy), f2s(C2));
            float2 num  = f2mul(N1, N2);
            float2 den  = f2mul(D1, D2);
            // one rcp for both columns: se = nx*dy/(dx*dy), so = ny*dx/(dx*dy)
            const float rdd = __builtin_amdgcn_rcpf(den.x * den.y);
            float2 s2 = make_float2(num.x * den.y * rdd,
                                    num.y * den.x * rdd);
            ls2 = f2fma(s2, vmask, ls2);
        }
    }

    float lsum = ls2.x + ls2.y;

    // ---- Block reduction: wave64 shuffle -> LDS -> one atomic/block ----
    #pragma unroll
    for (int off = 32; off > 0; off >>= 1)
        lsum += __shfl_down(lsum, off, 64);
    if ((tid & 63) == 0) red[tid >> 6] = lsum;
    __syncthreads();
    if (tid == 0) {
        float bs = 0.f;
        #pragma unroll
        for (int k = 0; k < BLOCK / 64; ++k) bs += red[k];
        atomicAdd(acc, bs);
    }
}

__global__ void finalize_kernel(const float* __restrict__ acc,
                                float* __restrict__ out)
{
    out[0] = 1.0f - acc[0] * (1.0f / (float)(NB * OH * OW));
}

extern "C" void kernel_launch(void* const* d_in, const int* in_sizes, int n_in,
                              void* d_out, int out_size, void* d_ws, size_t ws_size,
                              hipStream_t stream) {
    const float* X  = (const float*)d_in[0];
    const float* Y  = (const float*)d_in[1];
    const float* dr = (const float*)d_in[2];
    float* out = (float*)d_out;
    float* acc = (float*)d_ws;

    hipMemsetAsync(acc, 0, sizeof(float), stream);

    dim3 grid(1, NSTRIP, NB);   // 32 x 64 = 2048 blocks
    dim3 block(BLOCK);          // 256 threads = 4 waves
    ssim_kernel<<<grid, block, 0, stream>>>(X, Y, dr, acc);
    finalize_kernel<<<1, 1, 0, stream>>>(acc, out);
}